// Round 1
// baseline (3013.131 us; speedup 1.0000x reference)
//
#include <hip/hip_runtime.h>

#define NN   50000
#define NE   262144
#define NOCP 32768
#define EAVA (NE - NOCP)   // 229376
#define NG   64
#define HD   128

__device__ __forceinline__ float elu_f(float v) { return v > 0.f ? v : (expf(v) - 1.f); }

// monotone float<->uint encoding for atomic max on signed floats
__device__ __forceinline__ unsigned fenc(float f) {
  unsigned u = __float_as_uint(f);
  return (u & 0x80000000u) ? ~u : (u | 0x80000000u);
}
__device__ __forceinline__ float fdec(unsigned u) {
  return __uint_as_float((u & 0x80000000u) ? (u & 0x7fffffffu) : ~u);
}

__global__ __launch_bounds__(256) void zero_f4(float4* __restrict__ p, int n4) {
  for (int i = blockIdx.x * 256 + threadIdx.x; i < n4; i += gridDim.x * 256)
    p[i] = make_float4(0.f, 0.f, 0.f, 0.f);
}

__global__ void init_small(unsigned* mx_enc, float* denom, unsigned* pmax_enc, int* amin) {
  int t = threadIdx.x;
  if (t < NG) { mx_enc[t] = 0u; denom[t] = 0.f; pmax_enc[t] = 0u; amin[t] = EAVA; }
}

// scatter x rows into xsum_all (all edges) and xsum_ocp (first NOCP edges)
__global__ __launch_bounds__(256) void scatter_kernel(const float* __restrict__ x,
    const int* __restrict__ ei, float* __restrict__ xs_all, float* __restrict__ xs_ocp) {
  int e = blockIdx.x * 8 + (threadIdx.x >> 5);
  int q = threadIdx.x & 31;
  int src = ei[e];
  int dst = ei[NE + e];
  float4 v = ((const float4*)(x + (size_t)src * HD))[q];
  float* pa = xs_all + (size_t)dst * HD + q * 4;
  atomicAdd(pa + 0, v.x); atomicAdd(pa + 1, v.y); atomicAdd(pa + 2, v.z); atomicAdd(pa + 3, v.w);
  if (e < NOCP) {
    float* po = xs_ocp + (size_t)dst * HD + q * 4;
    atomicAdd(po + 0, v.x); atomicAdd(po + 1, v.y); atomicAdd(po + 2, v.z); atomicAdd(po + 3, v.w);
  }
}

// reps[n] = elu(x@Wself + xs_all@Wnbr + b) - elu(x@Wself + xs_ocp@Wnbr + b)
// fused dual-accumulator GEMM, 64x64 tile, K=256 logical (first 128: x/Wself, last 128: xs/Wnbr)
__global__ __launch_bounds__(256) void reps_kernel(const float* __restrict__ x,
    const float* __restrict__ xs_all, const float* __restrict__ xs_ocp,
    const float* __restrict__ Wself, const float* __restrict__ Wnbr,
    const float* __restrict__ bias, float* __restrict__ reps) {
  __shared__ float As1[16][68], As2[16][68], Bs[16][80];
  const int tid = threadIdx.x;
  const int bm = blockIdx.x * 64, bn = blockIdx.y * 64;
  float acc1[16], acc2[16];
#pragma unroll
  for (int i = 0; i < 16; ++i) { acc1[i] = 0.f; acc2[i] = 0.f; }
  const int ar = tid >> 2, acq = tid & 3;
  const int gm = bm + ar;
  const bool mval = gm < NN;
  const int bkr = tid >> 4, bcq = (tid & 15) << 2;
  const int tm = (tid & 15) << 2, tn = (tid >> 4) << 2;
  for (int kt = 0; kt < 256; kt += 16) {
    const bool sec = kt >= 128;
    const int kk = (kt & 127) + acq * 4;
    float4 a1 = make_float4(0, 0, 0, 0), a2 = a1;
    if (mval) {
      a1 = *(const float4*)((sec ? xs_all : x) + (size_t)gm * HD + kk);
      a2 = *(const float4*)((sec ? xs_ocp : x) + (size_t)gm * HD + kk);
    }
    float4 bv = *(const float4*)((sec ? Wnbr : Wself) + (size_t)((kt & 127) + bkr) * HD + bn + bcq);
    __syncthreads();
    int kb = acq * 4;
    As1[kb + 0][ar] = a1.x; As1[kb + 1][ar] = a1.y; As1[kb + 2][ar] = a1.z; As1[kb + 3][ar] = a1.w;
    As2[kb + 0][ar] = a2.x; As2[kb + 1][ar] = a2.y; As2[kb + 2][ar] = a2.z; As2[kb + 3][ar] = a2.w;
    *(float4*)&Bs[bkr][bcq] = bv;
    __syncthreads();
#pragma unroll
    for (int k = 0; k < 16; ++k) {
      float4 a1v = *(const float4*)&As1[k][tm];
      float4 a2v = *(const float4*)&As2[k][tm];
      float4 bv4 = *(const float4*)&Bs[k][tn];
      float aa1[4] = {a1v.x, a1v.y, a1v.z, a1v.w};
      float aa2[4] = {a2v.x, a2v.y, a2v.z, a2v.w};
      float bb4[4] = {bv4.x, bv4.y, bv4.z, bv4.w};
#pragma unroll
      for (int i = 0; i < 4; ++i) {
#pragma unroll
        for (int j = 0; j < 4; ++j) {
          acc1[i * 4 + j] += aa1[i] * bb4[j];
          acc2[i * 4 + j] += aa2[i] * bb4[j];
        }
      }
    }
  }
#pragma unroll
  for (int i = 0; i < 4; ++i) {
    int row = bm + tm + i;
    if (row < NN) {
      float o[4];
#pragma unroll
      for (int j = 0; j < 4; ++j) {
        float b = bias[bn + tn + j];
        o[j] = elu_f(acc1[i * 4 + j] + b) - elu_f(acc2[i * 4 + j] + b);
      }
      *(float4*)(reps + (size_t)row * HD + bn + tn) = make_float4(o[0], o[1], o[2], o[3]);
    }
  }
}

// generic fp32 GEMM C = act(A@B + bias), 128x128 tile, 8x8 microtile.
// MODE 0: A is M x K row-major.
// MODE 2: A row m = concat(reps[idx0[m]], reps[idx1[m]]) (K must be 256, reps rows HD wide)
template <int MODE, bool ACT>
__global__ __launch_bounds__(256) void gemm_bias_act(
    const float* __restrict__ A, const int* __restrict__ idx0, const int* __restrict__ idx1,
    const float* __restrict__ B, const float* __restrict__ bias, float* __restrict__ C,
    int M, int N, int K) {
  __shared__ float As[16][132];
  __shared__ float Bs[16][132];
  const int tid = threadIdx.x;
  const int bm = blockIdx.x * 128, bn = blockIdx.y * 128;
  float acc[8][8];
#pragma unroll
  for (int i = 0; i < 8; ++i)
#pragma unroll
    for (int j = 0; j < 8; ++j) acc[i][j] = 0.f;
  const int ar = tid >> 2, acq = tid & 3;
  const int gm0 = bm + ar, gm1 = bm + ar + 64;
  const bool v0 = gm0 < M, v1 = gm1 < M;
  int i00 = 0, i01 = 0, i10 = 0, i11 = 0;
  if (MODE == 2) {
    if (v0) { i00 = idx0[gm0]; i01 = idx1[gm0]; }
    if (v1) { i10 = idx0[gm1]; i11 = idx1[gm1]; }
  }
  const int bkr = tid >> 5, bcq = (tid & 31) << 2;
  const int tm = (tid & 15) << 3, tn = (tid >> 4) << 3;
  for (int kt = 0; kt < K; kt += 16) {
    float4 a0 = make_float4(0, 0, 0, 0), a1 = a0;
    int gk = kt + acq * 4;
    if (MODE == 0) {
      if (v0) a0 = *(const float4*)(A + (size_t)gm0 * K + gk);
      if (v1) a1 = *(const float4*)(A + (size_t)gm1 * K + gk);
    } else {
      int kk = gk & 127;
      if (v0) a0 = *(const float4*)(A + (size_t)(gk < 128 ? i00 : i01) * HD + kk);
      if (v1) a1 = *(const float4*)(A + (size_t)(gk < 128 ? i10 : i11) * HD + kk);
    }
    float4 b0 = *(const float4*)(B + (size_t)(kt + bkr) * N + bn + bcq);
    float4 b1 = *(const float4*)(B + (size_t)(kt + bkr + 8) * N + bn + bcq);
    __syncthreads();
    int kb = acq * 4;
    As[kb + 0][ar] = a0.x; As[kb + 1][ar] = a0.y; As[kb + 2][ar] = a0.z; As[kb + 3][ar] = a0.w;
    As[kb + 0][ar + 64] = a1.x; As[kb + 1][ar + 64] = a1.y; As[kb + 2][ar + 64] = a1.z; As[kb + 3][ar + 64] = a1.w;
    *(float4*)&Bs[bkr][bcq] = b0;
    *(float4*)&Bs[bkr + 8][bcq] = b1;
    __syncthreads();
#pragma unroll
    for (int k = 0; k < 16; ++k) {
      float4 x0 = *(const float4*)&As[k][tm];
      float4 x1 = *(const float4*)&As[k][tm + 4];
      float4 y0 = *(const float4*)&Bs[k][tn];
      float4 y1 = *(const float4*)&Bs[k][tn + 4];
      float av[8] = {x0.x, x0.y, x0.z, x0.w, x1.x, x1.y, x1.z, x1.w};
      float bv[8] = {y0.x, y0.y, y0.z, y0.w, y1.x, y1.y, y1.z, y1.w};
#pragma unroll
      for (int i = 0; i < 8; ++i)
#pragma unroll
        for (int j = 0; j < 8; ++j) acc[i][j] += av[i] * bv[j];
    }
  }
  float bb[8];
#pragma unroll
  for (int j = 0; j < 8; ++j) bb[j] = bias[bn + tn + j];
#pragma unroll
  for (int i = 0; i < 8; ++i) {
    int row = bm + tm + i;
    if (row < M) {
      float o[8];
#pragma unroll
      for (int j = 0; j < 8; ++j) { o[j] = acc[i][j] + bb[j]; if (ACT) o[j] = elu_f(o[j]); }
      float* cp = C + (size_t)row * N + bn + tn;
      *(float4*)cp = make_float4(o[0], o[1], o[2], o[3]);
      *(float4*)(cp + 4) = make_float4(o[4], o[5], o[6], o[7]);
    }
  }
}

// sel[e] = h[e] @ Wp2[:, y[batch_vec[src[e]]]] + bp2[c]; also store seg[e]. One wave per edge.
__global__ __launch_bounds__(256) void sel_kernel(const float* __restrict__ h,
    const int* __restrict__ ei, const int* __restrict__ batchv, const int* __restrict__ yv,
    const float* __restrict__ Wp2, const float* __restrict__ bp2,
    float* __restrict__ sel, int* __restrict__ seg, int count, int chunk_off) {
  int w = blockIdx.x * 4 + (threadIdx.x >> 6);
  int lane = threadIdx.x & 63;
  if (w >= count) return;
  int eg = chunk_off + w;
  int s = ei[NOCP + eg];
  int g = batchv[s];
  int c = yv[g];
  const float* hr = h + (size_t)w * HD;
  float a = hr[lane] * Wp2[lane * 10 + c] + hr[lane + 64] * Wp2[(lane + 64) * 10 + c];
#pragma unroll
  for (int o = 32; o > 0; o >>= 1) a += __shfl_xor(a, o);
  if (lane == 0) { sel[eg] = a + bp2[c]; seg[eg] = g; }
}

__global__ __launch_bounds__(256) void segmax_sel(const float* __restrict__ sel,
    const int* __restrict__ seg, unsigned* __restrict__ mx_enc) {
  __shared__ unsigned sm[NG];
  int tid = threadIdx.x;
  if (tid < NG) sm[tid] = 0u;
  __syncthreads();
  for (int i = blockIdx.x * blockDim.x + tid; i < EAVA; i += gridDim.x * blockDim.x)
    atomicMax(&sm[seg[i]], fenc(sel[i]));
  __syncthreads();
  if (tid < NG) atomicMax(&mx_enc[tid], sm[tid]);
}

__global__ __launch_bounds__(256) void exden_kernel(const float* __restrict__ sel,
    const int* __restrict__ seg, const unsigned* __restrict__ mx_enc,
    float* __restrict__ denom, float* __restrict__ out_probs) {
  __shared__ float sd[NG];
  __shared__ float smx[NG];
  int tid = threadIdx.x;
  if (tid < NG) { smx[tid] = fdec(mx_enc[tid]); sd[tid] = 0.f; }
  __syncthreads();
  for (int i = blockIdx.x * blockDim.x + tid; i < EAVA; i += gridDim.x * blockDim.x) {
    int g = seg[i];
    float ex = expf(sel[i] - smx[g]);
    out_probs[i] = ex;
    atomicAdd(&sd[g], ex);
  }
  __syncthreads();
  if (tid < NG) atomicAdd(&denom[tid], sd[tid]);
}

__global__ __launch_bounds__(256) void probpmax_kernel(const int* __restrict__ seg,
    const float* __restrict__ denom, float* __restrict__ out_probs,
    unsigned* __restrict__ pmax_enc) {
  __shared__ float sden[NG];
  __shared__ unsigned sp[NG];
  int tid = threadIdx.x;
  if (tid < NG) { sden[tid] = denom[tid]; sp[tid] = 0u; }
  __syncthreads();
  for (int i = blockIdx.x * blockDim.x + tid; i < EAVA; i += gridDim.x * blockDim.x) {
    int g = seg[i];
    float p = out_probs[i] / sden[g];
    out_probs[i] = p;
    atomicMax(&sp[g], fenc(p));
  }
  __syncthreads();
  if (tid < NG) atomicMax(&pmax_enc[tid], sp[tid]);
}

__global__ __launch_bounds__(256) void argmin_kernel(const int* __restrict__ seg,
    const float* __restrict__ out_probs, const unsigned* __restrict__ pmax_enc,
    int* __restrict__ amin) {
  __shared__ float spm[NG];
  __shared__ int sa[NG];
  int tid = threadIdx.x;
  if (tid < NG) { spm[tid] = fdec(pmax_enc[tid]); sa[tid] = EAVA; }
  __syncthreads();
  for (int i = blockIdx.x * blockDim.x + tid; i < EAVA; i += gridDim.x * blockDim.x) {
    int g = seg[i];
    if (out_probs[i] == spm[g]) atomicMin(&sa[g], i);
  }
  __syncthreads();
  if (tid < NG) atomicMin(&amin[tid], sa[tid]);
}

__global__ void finalize_kernel(const unsigned* __restrict__ pmax_enc,
    const int* __restrict__ amin, float* __restrict__ out) {
  int g = threadIdx.x;
  if (g < NG) {
    out[EAVA + g] = fdec(pmax_enc[g]);
    out[EAVA + NG + g] = (float)amin[g];
  }
}

extern "C" void kernel_launch(void* const* d_in, const int* in_sizes, int n_in,
                              void* d_out, int out_size, void* d_ws, size_t ws_size,
                              hipStream_t stream) {
  const float* x      = (const float*)d_in[0];
  const int*   ei     = (const int*)d_in[1];
  const int*   batchv = (const int*)d_in[2];
  const int*   yv     = (const int*)d_in[3];
  // d_in[4] = n_ocp device scalar; fixed at 32768 by the reference constants
  const float* Wself = (const float*)d_in[5];
  const float* Wnbr  = (const float*)d_in[6];
  const float* bgnn  = (const float*)d_in[7];
  const float* Wr1   = (const float*)d_in[8];
  const float* br1   = (const float*)d_in[9];
  const float* Wr2   = (const float*)d_in[10];
  const float* br2   = (const float*)d_in[11];
  const float* Wr3   = (const float*)d_in[12];
  const float* br3   = (const float*)d_in[13];
  const float* Wp1   = (const float*)d_in[14];
  const float* bp1   = (const float*)d_in[15];
  const float* Wp2   = (const float*)d_in[16];
  const float* bp2   = (const float*)d_in[17];
  float* out = (float*)d_out;

  char* wp = (char*)d_ws;
  auto alloc = [&](size_t bytes) -> char* {
    char* p = wp;
    wp += (bytes + 255) & ~(size_t)255;
    return p;
  };
  float*    xs_all   = (float*)alloc((size_t)NN * HD * 4);
  float*    xs_ocp   = (float*)alloc((size_t)NN * HD * 4);
  float*    reps     = (float*)alloc((size_t)NN * HD * 4);
  float*    sel      = (float*)alloc((size_t)EAVA * 4);
  int*      seg      = (int*)alloc((size_t)EAVA * 4);
  unsigned* mx_enc   = (unsigned*)alloc(NG * 4);
  float*    denom    = (float*)alloc(NG * 4);
  unsigned* pmax_enc = (unsigned*)alloc(NG * 4);
  int*      amin     = (int*)alloc(NG * 4);

  size_t used  = (size_t)(wp - (char*)d_ws);
  size_t avail = ws_size > used ? ws_size - used : 0;
  long long chv = (long long)(avail / 4096);  // bytes per edge of chunk scratch: (512+256+128+128)*4
  int CH = chv > 32768 ? 32768 : (int)chv;
  CH &= ~127;
  if (CH < 128) CH = 128;
  float* b1 = (float*)alloc((size_t)CH * 512 * 4);
  float* b2 = (float*)alloc((size_t)CH * 256 * 4);
  float* b3 = (float*)alloc((size_t)CH * 128 * 4);
  float* b4 = (float*)alloc((size_t)CH * 128 * 4);

  // init: zero xs_all + xs_ocp (contiguous), init small reduction arrays
  zero_f4<<<2048, 256, 0, stream>>>((float4*)xs_all, (int)((size_t)NN * HD * 2 / 4));
  init_small<<<1, 64, 0, stream>>>(mx_enc, denom, pmax_enc, amin);

  // GNN: scatter + fused dual GEMM + elu-diff
  scatter_kernel<<<NE / 8, 256, 0, stream>>>(x, ei, xs_all, xs_ocp);
  reps_kernel<<<dim3((NN + 63) / 64, 2), 256, 0, stream>>>(x, xs_all, xs_ocp, Wself, Wnbr, bgnn, reps);

  // per-edge MLP in chunks
  for (int co = 0; co < EAVA; co += CH) {
    int cnt = EAVA - co;
    if (cnt > CH) cnt = CH;
    int gx = (cnt + 127) / 128;
    gemm_bias_act<2, true><<<dim3(gx, 4), 256, 0, stream>>>(reps, ei + NOCP + co, ei + NE + NOCP + co,
                                                            Wr1, br1, b1, cnt, 512, 256);
    gemm_bias_act<0, true><<<dim3(gx, 2), 256, 0, stream>>>(b1, nullptr, nullptr, Wr2, br2, b2, cnt, 256, 512);
    gemm_bias_act<0, false><<<dim3(gx, 1), 256, 0, stream>>>(b2, nullptr, nullptr, Wr3, br3, b3, cnt, 128, 256);
    gemm_bias_act<0, true><<<dim3(gx, 1), 256, 0, stream>>>(b3, nullptr, nullptr, Wp1, bp1, b4, cnt, 128, 128);
    sel_kernel<<<(cnt + 3) / 4, 256, 0, stream>>>(b4, ei, batchv, yv, Wp2, bp2, sel, seg, cnt, co);
  }

  // segment softmax + argmax bookkeeping
  segmax_sel<<<112, 256, 0, stream>>>(sel, seg, mx_enc);
  exden_kernel<<<112, 256, 0, stream>>>(sel, seg, mx_enc, denom, out);
  probpmax_kernel<<<112, 256, 0, stream>>>(seg, denom, out, pmax_enc);
  argmin_kernel<<<112, 256, 0, stream>>>(seg, out, pmax_enc, amin);
  finalize_kernel<<<1, 64, 0, stream>>>(pmax_enc, amin, out);
}

// Round 2
// 2405.070 us; speedup vs baseline: 1.2528x; 1.2528x over previous
//
#include <hip/hip_runtime.h>

#define NN   50000
#define NE   262144
#define NOCP 32768
#define EAVA (NE - NOCP)   // 229376
#define NG   64
#define HD   128
#define CAP  48            // per-node edge bucket capacity (Poisson(5.24) overflow ~1e-15)

__device__ __forceinline__ float elu_f(float v) { return v > 0.f ? v : (expf(v) - 1.f); }

// monotone float<->uint encoding for atomic max on signed floats
__device__ __forceinline__ unsigned fenc(float f) {
  unsigned u = __float_as_uint(f);
  return (u & 0x80000000u) ? ~u : (u | 0x80000000u);
}
__device__ __forceinline__ float fdec(unsigned u) {
  return __uint_as_float((u & 0x80000000u) ? (u & 0x7fffffffu) : ~u);
}

__global__ __launch_bounds__(256) void zero_i(int* __restrict__ p, int n) {
  for (int i = blockIdx.x * 256 + threadIdx.x; i < n; i += gridDim.x * 256) p[i] = 0;
}

__global__ void init_small(unsigned* mx_enc, float* denom, unsigned* pmax_enc, int* amin) {
  int t = threadIdx.x;
  if (t < NG) { mx_enc[t] = 0u; denom[t] = 0.f; pmax_enc[t] = 0u; amin[t] = EAVA; }
}

// pass 1: count + fill per-dst edge buckets (int atomics only)
__global__ __launch_bounds__(256) void bucket_kernel(const int* __restrict__ ei,
    int* __restrict__ cnt, int* __restrict__ bucket) {
  int e = blockIdx.x * 256 + threadIdx.x;
  if (e >= NE) return;
  int dst = ei[NE + e];
  int slot = atomicAdd(&cnt[dst], 1);
  if (slot < CAP) bucket[(size_t)dst * CAP + slot] = e;
}

// pass 2: one wave per node, gather source rows, write xs_all / xs_ocp once
__global__ __launch_bounds__(256) void gather_kernel(const float* __restrict__ x,
    const int* __restrict__ ei, const int* __restrict__ cnt, const int* __restrict__ bucket,
    float* __restrict__ xs_all, float* __restrict__ xs_ocp) {
  int n = blockIdx.x * 4 + (threadIdx.x >> 6);
  if (n >= NN) return;
  int lane = threadIdx.x & 63;
  int c = cnt[n];
  if (c > CAP) c = CAP;
  float2 aall = make_float2(0.f, 0.f), aocp = aall;
  const int* bk = bucket + (size_t)n * CAP;
  for (int i = 0; i < c; ++i) {
    int e = bk[i];                 // wave-uniform broadcast load
    int src = ei[e];
    float2 v = *(const float2*)(x + (size_t)src * HD + lane * 2);
    aall.x += v.x; aall.y += v.y;
    if (e < NOCP) { aocp.x += v.x; aocp.y += v.y; }
  }
  *(float2*)(xs_all + (size_t)n * HD + lane * 2) = aall;
  *(float2*)(xs_ocp + (size_t)n * HD + lane * 2) = aocp;
}

// reps[n] = elu(x@Wself + xs_all@Wnbr + b) - elu(x@Wself + xs_ocp@Wnbr + b)
__global__ __launch_bounds__(256) void reps_kernel(const float* __restrict__ x,
    const float* __restrict__ xs_all, const float* __restrict__ xs_ocp,
    const float* __restrict__ Wself, const float* __restrict__ Wnbr,
    const float* __restrict__ bias, float* __restrict__ reps) {
  __shared__ float As1[16][68], As2[16][68], Bs[16][80];
  const int tid = threadIdx.x;
  const int bm = blockIdx.x * 64, bn = blockIdx.y * 64;
  float acc1[16], acc2[16];
#pragma unroll
  for (int i = 0; i < 16; ++i) { acc1[i] = 0.f; acc2[i] = 0.f; }
  const int ar = tid >> 2, acq = tid & 3;
  const int gm = bm + ar;
  const bool mval = gm < NN;
  const int bkr = tid >> 4, bcq = (tid & 15) << 2;
  const int tm = (tid & 15) << 2, tn = (tid >> 4) << 2;
  for (int kt = 0; kt < 256; kt += 16) {
    const bool sec = kt >= 128;
    const int kk = (kt & 127) + acq * 4;
    float4 a1 = make_float4(0, 0, 0, 0), a2 = a1;
    if (mval) {
      a1 = *(const float4*)((sec ? xs_all : x) + (size_t)gm * HD + kk);
      a2 = *(const float4*)((sec ? xs_ocp : x) + (size_t)gm * HD + kk);
    }
    float4 bv = *(const float4*)((sec ? Wnbr : Wself) + (size_t)((kt & 127) + bkr) * HD + bn + bcq);
    __syncthreads();
    int kb = acq * 4;
    As1[kb + 0][ar] = a1.x; As1[kb + 1][ar] = a1.y; As1[kb + 2][ar] = a1.z; As1[kb + 3][ar] = a1.w;
    As2[kb + 0][ar] = a2.x; As2[kb + 1][ar] = a2.y; As2[kb + 2][ar] = a2.z; As2[kb + 3][ar] = a2.w;
    *(float4*)&Bs[bkr][bcq] = bv;
    __syncthreads();
#pragma unroll
    for (int k = 0; k < 16; ++k) {
      float4 a1v = *(const float4*)&As1[k][tm];
      float4 a2v = *(const float4*)&As2[k][tm];
      float4 bv4 = *(const float4*)&Bs[k][tn];
      float aa1[4] = {a1v.x, a1v.y, a1v.z, a1v.w};
      float aa2[4] = {a2v.x, a2v.y, a2v.z, a2v.w};
      float bb4[4] = {bv4.x, bv4.y, bv4.z, bv4.w};
#pragma unroll
      for (int i = 0; i < 4; ++i) {
#pragma unroll
        for (int j = 0; j < 4; ++j) {
          acc1[i * 4 + j] += aa1[i] * bb4[j];
          acc2[i * 4 + j] += aa2[i] * bb4[j];
        }
      }
    }
  }
#pragma unroll
  for (int i = 0; i < 4; ++i) {
    int row = bm + tm + i;
    if (row < NN) {
      float o[4];
#pragma unroll
      for (int j = 0; j < 4; ++j) {
        float b = bias[bn + tn + j];
        o[j] = elu_f(acc1[i * 4 + j] + b) - elu_f(acc2[i * 4 + j] + b);
      }
      *(float4*)(reps + (size_t)row * HD + bn + tn) = make_float4(o[0], o[1], o[2], o[3]);
    }
  }
}

// fp32 GEMM C = act(A@B + bias), 128x128 tile, 8x8 microtile, conflict-free
// fragment layout: rows {rm..rm+3, rm+64..rm+67}, cols {cn..cn+3, cn+64..cn+67}.
// MODE 0: A is M x K row-major.
// MODE 2: A row m = concat(reps[idx0[m]], reps[idx1[m]]) (K=256, reps rows HD wide)
template <int MODE, bool ACT>
__global__ __launch_bounds__(256) void gemm_bias_act(
    const float* __restrict__ A, const int* __restrict__ idx0, const int* __restrict__ idx1,
    const float* __restrict__ B, const float* __restrict__ bias, float* __restrict__ C,
    int M, int N, int K) {
  __shared__ float As[16][132];
  __shared__ float Bs[16][132];
  const int tid = threadIdx.x;
  const int bm = blockIdx.x * 128, bn = blockIdx.y * 128;
  float acc[8][8];
#pragma unroll
  for (int i = 0; i < 8; ++i)
#pragma unroll
    for (int j = 0; j < 8; ++j) acc[i][j] = 0.f;
  const int ar = tid >> 2, acq = tid & 3;
  const int gm0 = bm + ar, gm1 = bm + ar + 64;
  const bool v0 = gm0 < M, v1 = gm1 < M;
  int i00 = 0, i01 = 0, i10 = 0, i11 = 0;
  if (MODE == 2) {
    if (v0) { i00 = idx0[gm0]; i01 = idx1[gm0]; }
    if (v1) { i10 = idx0[gm1]; i11 = idx1[gm1]; }
  }
  const int bkr = tid >> 5, bcq = (tid & 31) << 2;
  const int rm = (tid & 15) << 2, cn = (tid >> 4) << 2;
  for (int kt = 0; kt < K; kt += 16) {
    float4 a0 = make_float4(0, 0, 0, 0), a1 = a0;
    int gk = kt + acq * 4;
    if (MODE == 0) {
      if (v0) a0 = *(const float4*)(A + (size_t)gm0 * K + gk);
      if (v1) a1 = *(const float4*)(A + (size_t)gm1 * K + gk);
    } else {
      int kk = gk & 127;
      if (v0) a0 = *(const float4*)(A + (size_t)(gk < 128 ? i00 : i01) * HD + kk);
      if (v1) a1 = *(const float4*)(A + (size_t)(gk < 128 ? i10 : i11) * HD + kk);
    }
    float4 b0 = *(const float4*)(B + (size_t)(kt + bkr) * N + bn + bcq);
    float4 b1 = *(const float4*)(B + (size_t)(kt + bkr + 8) * N + bn + bcq);
    __syncthreads();
    int kb = acq * 4;
    As[kb + 0][ar] = a0.x; As[kb + 1][ar] = a0.y; As[kb + 2][ar] = a0.z; As[kb + 3][ar] = a0.w;
    As[kb + 0][ar + 64] = a1.x; As[kb + 1][ar + 64] = a1.y; As[kb + 2][ar + 64] = a1.z; As[kb + 3][ar + 64] = a1.w;
    *(float4*)&Bs[bkr][bcq] = b0;
    *(float4*)&Bs[bkr + 8][bcq] = b1;
    __syncthreads();
#pragma unroll
    for (int k = 0; k < 16; ++k) {
      float4 x0 = *(const float4*)&As[k][rm];
      float4 x1 = *(const float4*)&As[k][rm + 64];
      float4 y0 = *(const float4*)&Bs[k][cn];
      float4 y1 = *(const float4*)&Bs[k][cn + 64];
      float av[8] = {x0.x, x0.y, x0.z, x0.w, x1.x, x1.y, x1.z, x1.w};
      float bv[8] = {y0.x, y0.y, y0.z, y0.w, y1.x, y1.y, y1.z, y1.w};
#pragma unroll
      for (int i = 0; i < 8; ++i)
#pragma unroll
        for (int j = 0; j < 8; ++j) acc[i][j] += av[i] * bv[j];
    }
  }
  float bb[8];
#pragma unroll
  for (int j = 0; j < 4; ++j) { bb[j] = bias[bn + cn + j]; bb[j + 4] = bias[bn + cn + 64 + j]; }
#pragma unroll
  for (int i = 0; i < 8; ++i) {
    int row = bm + (i < 4 ? rm + i : rm + 60 + i);  // i>=4 -> rm+64+(i-4)
    if (row < M) {
      float o[8];
#pragma unroll
      for (int j = 0; j < 8; ++j) { o[j] = acc[i][j] + bb[j]; if (ACT) o[j] = elu_f(o[j]); }
      float* cp = C + (size_t)row * N + bn + cn;
      *(float4*)cp = make_float4(o[0], o[1], o[2], o[3]);
      *(float4*)(cp + 64) = make_float4(o[4], o[5], o[6], o[7]);
    }
  }
}

// sel[e] = h[e] @ Wp2[:, y[batch_vec[src[e]]]] + bp2[c]; also store seg[e]. One wave per edge.
__global__ __launch_bounds__(256) void sel_kernel(const float* __restrict__ h,
    const int* __restrict__ ei, const int* __restrict__ batchv, const int* __restrict__ yv,
    const float* __restrict__ Wp2, const float* __restrict__ bp2,
    float* __restrict__ sel, int* __restrict__ seg, int count, int chunk_off) {
  int w = blockIdx.x * 4 + (threadIdx.x >> 6);
  int lane = threadIdx.x & 63;
  if (w >= count) return;
  int eg = chunk_off + w;
  int s = ei[NOCP + eg];
  int g = batchv[s];
  int c = yv[g];
  const float* hr = h + (size_t)w * HD;
  float a = hr[lane] * Wp2[lane * 10 + c] + hr[lane + 64] * Wp2[(lane + 64) * 10 + c];
#pragma unroll
  for (int o = 32; o > 0; o >>= 1) a += __shfl_xor(a, o);
  if (lane == 0) { sel[eg] = a + bp2[c]; seg[eg] = g; }
}

__global__ __launch_bounds__(256) void segmax_sel(const float* __restrict__ sel,
    const int* __restrict__ seg, unsigned* __restrict__ mx_enc) {
  __shared__ unsigned sm[NG];
  int tid = threadIdx.x;
  if (tid < NG) sm[tid] = 0u;
  __syncthreads();
  for (int i = blockIdx.x * blockDim.x + tid; i < EAVA; i += gridDim.x * blockDim.x)
    atomicMax(&sm[seg[i]], fenc(sel[i]));
  __syncthreads();
  if (tid < NG) atomicMax(&mx_enc[tid], sm[tid]);
}

__global__ __launch_bounds__(256) void exden_kernel(const float* __restrict__ sel,
    const int* __restrict__ seg, const unsigned* __restrict__ mx_enc,
    float* __restrict__ denom, float* __restrict__ out_probs) {
  __shared__ float sd[NG];
  __shared__ float smx[NG];
  int tid = threadIdx.x;
  if (tid < NG) { smx[tid] = fdec(mx_enc[tid]); sd[tid] = 0.f; }
  __syncthreads();
  for (int i = blockIdx.x * blockDim.x + tid; i < EAVA; i += gridDim.x * blockDim.x) {
    int g = seg[i];
    float ex = expf(sel[i] - smx[g]);
    out_probs[i] = ex;
    atomicAdd(&sd[g], ex);
  }
  __syncthreads();
  if (tid < NG) atomicAdd(&denom[tid], sd[tid]);
}

__global__ __launch_bounds__(256) void probpmax_kernel(const int* __restrict__ seg,
    const float* __restrict__ denom, float* __restrict__ out_probs,
    unsigned* __restrict__ pmax_enc) {
  __shared__ float sden[NG];
  __shared__ unsigned sp[NG];
  int tid = threadIdx.x;
  if (tid < NG) { sden[tid] = denom[tid]; sp[tid] = 0u; }
  __syncthreads();
  for (int i = blockIdx.x * blockDim.x + tid; i < EAVA; i += gridDim.x * blockDim.x) {
    int g = seg[i];
    float p = out_probs[i] / sden[g];
    out_probs[i] = p;
    atomicMax(&sp[g], fenc(p));
  }
  __syncthreads();
  if (tid < NG) atomicMax(&pmax_enc[tid], sp[tid]);
}

__global__ __launch_bounds__(256) void argmin_kernel(const int* __restrict__ seg,
    const float* __restrict__ out_probs, const unsigned* __restrict__ pmax_enc,
    int* __restrict__ amin) {
  __shared__ float spm[NG];
  __shared__ int sa[NG];
  int tid = threadIdx.x;
  if (tid < NG) { spm[tid] = fdec(pmax_enc[tid]); sa[tid] = EAVA; }
  __syncthreads();
  for (int i = blockIdx.x * blockDim.x + tid; i < EAVA; i += gridDim.x * blockDim.x) {
    int g = seg[i];
    if (out_probs[i] == spm[g]) atomicMin(&sa[g], i);
  }
  __syncthreads();
  if (tid < NG) atomicMin(&amin[tid], sa[tid]);
}

__global__ void finalize_kernel(const unsigned* __restrict__ pmax_enc,
    const int* __restrict__ amin, float* __restrict__ out) {
  int g = threadIdx.x;
  if (g < NG) {
    out[EAVA + g] = fdec(pmax_enc[g]);
    out[EAVA + NG + g] = (float)amin[g];
  }
}

extern "C" void kernel_launch(void* const* d_in, const int* in_sizes, int n_in,
                              void* d_out, int out_size, void* d_ws, size_t ws_size,
                              hipStream_t stream) {
  const float* x      = (const float*)d_in[0];
  const int*   ei     = (const int*)d_in[1];
  const int*   batchv = (const int*)d_in[2];
  const int*   yv     = (const int*)d_in[3];
  const float* Wself = (const float*)d_in[5];
  const float* Wnbr  = (const float*)d_in[6];
  const float* bgnn  = (const float*)d_in[7];
  const float* Wr1   = (const float*)d_in[8];
  const float* br1   = (const float*)d_in[9];
  const float* Wr2   = (const float*)d_in[10];
  const float* br2   = (const float*)d_in[11];
  const float* Wr3   = (const float*)d_in[12];
  const float* br3   = (const float*)d_in[13];
  const float* Wp1   = (const float*)d_in[14];
  const float* bp1   = (const float*)d_in[15];
  const float* Wp2   = (const float*)d_in[16];
  const float* bp2   = (const float*)d_in[17];
  float* out = (float*)d_out;

  char* wp = (char*)d_ws;
  auto alloc = [&](size_t bytes) -> char* {
    char* p = wp;
    wp += (bytes + 255) & ~(size_t)255;
    return p;
  };
  float*    xs_all   = (float*)alloc((size_t)NN * HD * 4);
  float*    xs_ocp   = (float*)alloc((size_t)NN * HD * 4);
  float*    reps     = (float*)alloc((size_t)NN * HD * 4);
  int*      cnt      = (int*)alloc((size_t)NN * 4);
  int*      bucket   = (int*)alloc((size_t)NN * CAP * 4);
  float*    sel      = (float*)alloc((size_t)EAVA * 4);
  int*      seg      = (int*)alloc((size_t)EAVA * 4);
  unsigned* mx_enc   = (unsigned*)alloc(NG * 4);
  float*    denom    = (float*)alloc(NG * 4);
  unsigned* pmax_enc = (unsigned*)alloc(NG * 4);
  int*      amin     = (int*)alloc(NG * 4);

  size_t used  = (size_t)(wp - (char*)d_ws);
  size_t avail = ws_size > used ? ws_size - used : 0;
  long long chv = (long long)(avail / 4096);  // bytes per edge: (512+256+128+128)*4
  int CH = chv > 32768 ? 32768 : (int)chv;
  CH &= ~127;
  if (CH < 128) CH = 128;
  float* b1 = (float*)alloc((size_t)CH * 512 * 4);
  float* b2 = (float*)alloc((size_t)CH * 256 * 4);
  float* b3 = (float*)alloc((size_t)CH * 128 * 4);
  float* b4 = (float*)alloc((size_t)CH * 128 * 4);

  // GNN aggregation: bucket-then-gather (no fp32 atomics)
  zero_i<<<64, 256, 0, stream>>>(cnt, NN);
  init_small<<<1, 64, 0, stream>>>(mx_enc, denom, pmax_enc, amin);
  bucket_kernel<<<NE / 256, 256, 0, stream>>>(ei, cnt, bucket);
  gather_kernel<<<(NN + 3) / 4, 256, 0, stream>>>(x, ei, cnt, bucket, xs_all, xs_ocp);
  reps_kernel<<<dim3((NN + 63) / 64, 2), 256, 0, stream>>>(x, xs_all, xs_ocp, Wself, Wnbr, bgnn, reps);

  // per-edge MLP in chunks
  for (int co = 0; co < EAVA; co += CH) {
    int cnt_e = EAVA - co;
    if (cnt_e > CH) cnt_e = CH;
    int gx = (cnt_e + 127) / 128;
    gemm_bias_act<2, true><<<dim3(gx, 4), 256, 0, stream>>>(reps, ei + NOCP + co, ei + NE + NOCP + co,
                                                            Wr1, br1, b1, cnt_e, 512, 256);
    gemm_bias_act<0, true><<<dim3(gx, 2), 256, 0, stream>>>(b1, nullptr, nullptr, Wr2, br2, b2, cnt_e, 256, 512);
    gemm_bias_act<0, false><<<dim3(gx, 1), 256, 0, stream>>>(b2, nullptr, nullptr, Wr3, br3, b3, cnt_e, 128, 256);
    gemm_bias_act<0, true><<<dim3(gx, 1), 256, 0, stream>>>(b3, nullptr, nullptr, Wp1, bp1, b4, cnt_e, 128, 128);
    sel_kernel<<<(cnt_e + 3) / 4, 256, 0, stream>>>(b4, ei, batchv, yv, Wp2, bp2, sel, seg, cnt_e, co);
  }

  // segment softmax + argmax bookkeeping
  segmax_sel<<<112, 256, 0, stream>>>(sel, seg, mx_enc);
  exden_kernel<<<112, 256, 0, stream>>>(sel, seg, mx_enc, denom, out);
  probpmax_kernel<<<112, 256, 0, stream>>>(seg, denom, out, pmax_enc);
  argmin_kernel<<<112, 256, 0, stream>>>(seg, out, pmax_enc, amin);
  finalize_kernel<<<1, 64, 0, stream>>>(pmax_enc, amin, out);
}

// Round 3
// 1095.666 us; speedup vs baseline: 2.7500x; 2.1951x over previous
//
#include <hip/hip_runtime.h>

#define NN   50000
#define NE   262144
#define NOCP 32768
#define EAVA (NE - NOCP)   // 229376 = 7 * 32768
#define NG   64
#define HD   128
#define CAP  48
#define CHNK 32768

typedef _Float16 f16x8 __attribute__((ext_vector_type(8)));
typedef float f32x4 __attribute__((ext_vector_type(4)));

__device__ __forceinline__ float elu_f(float v) { return v > 0.f ? v : (expf(v) - 1.f); }

__device__ __forceinline__ unsigned fenc(float f) {
  unsigned u = __float_as_uint(f);
  return (u & 0x80000000u) ? ~u : (u | 0x80000000u);
}
__device__ __forceinline__ float fdec(unsigned u) {
  return __uint_as_float((u & 0x80000000u) ? (u & 0x7fffffffu) : ~u);
}

// async global->LDS 16B per lane; LDS dst = base + lane*16 (wave-uniform base)
__device__ __forceinline__ void dma16(const void* g, void* l) {
  __builtin_amdgcn_global_load_lds((const __attribute__((address_space(1))) unsigned int*)g,
                                   (__attribute__((address_space(3))) unsigned int*)l,
                                   16, 0, 0);
}

__global__ __launch_bounds__(256) void zero_i(int* __restrict__ p, int n) {
  for (int i = blockIdx.x * 256 + threadIdx.x; i < n; i += gridDim.x * 256) p[i] = 0;
}

__global__ void init_small(unsigned* mx_enc, float* denom, unsigned* pmax_enc, int* amin) {
  int t = threadIdx.x;
  if (t < NG) { mx_enc[t] = 0u; denom[t] = 0.f; pmax_enc[t] = 0u; amin[t] = EAVA; }
}

// ---------------- GNN aggregation (bucket-then-gather, fp32) ----------------
__global__ __launch_bounds__(256) void bucket_kernel(const int* __restrict__ ei,
    int* __restrict__ cnt, int* __restrict__ bucket) {
  int e = blockIdx.x * 256 + threadIdx.x;
  if (e >= NE) return;
  int dst = ei[NE + e];
  int slot = atomicAdd(&cnt[dst], 1);
  if (slot < CAP) bucket[(size_t)dst * CAP + slot] = e;
}

__global__ __launch_bounds__(256) void gather_kernel(const float* __restrict__ x,
    const int* __restrict__ ei, const int* __restrict__ cnt, const int* __restrict__ bucket,
    float* __restrict__ xs_all, float* __restrict__ xs_ocp) {
  int n = blockIdx.x * 4 + (threadIdx.x >> 6);
  if (n >= NN) return;
  int lane = threadIdx.x & 63;
  int c = cnt[n];
  if (c > CAP) c = CAP;
  float2 aall = make_float2(0.f, 0.f), aocp = aall;
  const int* bk = bucket + (size_t)n * CAP;
  for (int i = 0; i < c; ++i) {
    int e = bk[i];
    int src = ei[e];
    float2 v = *(const float2*)(x + (size_t)src * HD + lane * 2);
    aall.x += v.x; aall.y += v.y;
    if (e < NOCP) { aocp.x += v.x; aocp.y += v.y; }
  }
  *(float2*)(xs_all + (size_t)n * HD + lane * 2) = aall;
  *(float2*)(xs_ocp + (size_t)n * HD + lane * 2) = aocp;
}

// reps[n] = elu(x@Wself + xs_all@Wnbr + b) - elu(x@Wself + xs_ocp@Wnbr + b)  (fp32)
__global__ __launch_bounds__(256) void reps_kernel(const float* __restrict__ x,
    const float* __restrict__ xs_all, const float* __restrict__ xs_ocp,
    const float* __restrict__ Wself, const float* __restrict__ Wnbr,
    const float* __restrict__ bias, float* __restrict__ reps) {
  __shared__ float As1[16][68], As2[16][68], Bs[16][80];
  const int tid = threadIdx.x;
  const int bm = blockIdx.x * 64, bn = blockIdx.y * 64;
  float acc1[16], acc2[16];
#pragma unroll
  for (int i = 0; i < 16; ++i) { acc1[i] = 0.f; acc2[i] = 0.f; }
  const int ar = tid >> 2, acq = tid & 3;
  const int gm = bm + ar;
  const bool mval = gm < NN;
  const int bkr = tid >> 4, bcq = (tid & 15) << 2;
  const int tm = (tid & 15) << 2, tn = (tid >> 4) << 2;
  for (int kt = 0; kt < 256; kt += 16) {
    const bool sec = kt >= 128;
    const int kk = (kt & 127) + acq * 4;
    float4 a1 = make_float4(0, 0, 0, 0), a2 = a1;
    if (mval) {
      a1 = *(const float4*)((sec ? xs_all : x) + (size_t)gm * HD + kk);
      a2 = *(const float4*)((sec ? xs_ocp : x) + (size_t)gm * HD + kk);
    }
    float4 bv = *(const float4*)((sec ? Wnbr : Wself) + (size_t)((kt & 127) + bkr) * HD + bn + bcq);
    __syncthreads();
    int kb = acq * 4;
    As1[kb + 0][ar] = a1.x; As1[kb + 1][ar] = a1.y; As1[kb + 2][ar] = a1.z; As1[kb + 3][ar] = a1.w;
    As2[kb + 0][ar] = a2.x; As2[kb + 1][ar] = a2.y; As2[kb + 2][ar] = a2.z; As2[kb + 3][ar] = a2.w;
    *(float4*)&Bs[bkr][bcq] = bv;
    __syncthreads();
#pragma unroll
    for (int k = 0; k < 16; ++k) {
      float4 a1v = *(const float4*)&As1[k][tm];
      float4 a2v = *(const float4*)&As2[k][tm];
      float4 bv4 = *(const float4*)&Bs[k][tn];
      float aa1[4] = {a1v.x, a1v.y, a1v.z, a1v.w};
      float aa2[4] = {a2v.x, a2v.y, a2v.z, a2v.w};
      float bb4[4] = {bv4.x, bv4.y, bv4.z, bv4.w};
#pragma unroll
      for (int i = 0; i < 4; ++i)
#pragma unroll
        for (int j = 0; j < 4; ++j) {
          acc1[i * 4 + j] += aa1[i] * bb4[j];
          acc2[i * 4 + j] += aa2[i] * bb4[j];
        }
    }
  }
#pragma unroll
  for (int i = 0; i < 4; ++i) {
    int row = bm + tm + i;
    if (row < NN) {
      float o[4];
#pragma unroll
      for (int j = 0; j < 4; ++j) {
        float b = bias[bn + tn + j];
        o[j] = elu_f(acc1[i * 4 + j] + b) - elu_f(acc2[i * 4 + j] + b);
      }
      *(float4*)(reps + (size_t)row * HD + bn + tn) = make_float4(o[0], o[1], o[2], o[3]);
    }
  }
}

// ---------------- fp16 split-precision helpers ----------------
// reps -> hi/lo fp16 row-major
__global__ __launch_bounds__(256) void split_reps(const float* __restrict__ r,
    _Float16* __restrict__ rh, _Float16* __restrict__ rl) {
  int t = blockIdx.x * 256 + threadIdx.x;
  if (t >= NN * HD / 8) return;
  const float4* p = (const float4*)(r + (size_t)t * 8);
  float4 v0 = p[0], v1 = p[1];
  float vv[8] = {v0.x, v0.y, v0.z, v0.w, v1.x, v1.y, v1.z, v1.w};
  f16x8 hv, lv;
#pragma unroll
  for (int j = 0; j < 8; ++j) {
    _Float16 hh = (_Float16)vv[j];
    hv[j] = hh;
    lv[j] = (_Float16)(vv[j] - (float)hh);
  }
  *(f16x8*)(rh + (size_t)t * 8) = hv;
  *(f16x8*)(rl + (size_t)t * 8) = lv;
}

// W34 = Wr3 @ Wp1 ; b34 = br3 @ Wp1 + bp1
__global__ void w34_kernel(const float* __restrict__ Wr3, const float* __restrict__ Wp1,
    const float* __restrict__ br3, const float* __restrict__ bp1,
    float* __restrict__ W34, float* __restrict__ b34) {
  int i = blockIdx.x, j = threadIdx.x;  // grid 256 x block 128
  float s = 0.f;
  for (int k = 0; k < 128; ++k) s += Wr3[i * 128 + k] * Wp1[k * 128 + j];
  W34[i * 128 + j] = s;
  if (i == 0) {
    float t = bp1[j];
    for (int k = 0; k < 128; ++k) t += br3[k] * Wp1[k * 128 + j];
    b34[j] = t;
  }
}

// pack W (KxN fp32 row-major) into MFMA-fragment order, hi/lo fp16.
// chunk = kt*(N/16)+ns; within chunk: lane L holds B[kt*32+(L>>4)*8 + j][ns*16+(L&15)]
__global__ void pack_w(const float* __restrict__ W, int K, int N,
    _Float16* __restrict__ oh, _Float16* __restrict__ ol) {
  int chunk = blockIdx.x;
  int lane = threadIdx.x;  // 64
  int NS = N >> 4;
  int ns = chunk % NS, kt = chunk / NS;
  int n = ns * 16 + (lane & 15);
  int k0 = kt * 32 + (lane >> 4) * 8;
  f16x8 hv, lv;
#pragma unroll
  for (int j = 0; j < 8; ++j) {
    float v = W[(size_t)(k0 + j) * N + n];
    _Float16 hh = (_Float16)v;
    hv[j] = hh;
    lv[j] = (_Float16)(v - (float)hh);
  }
  *(f16x8*)(oh + (size_t)chunk * 512 + lane * 8) = hv;
  *(f16x8*)(ol + (size_t)chunk * 512 + lane * 8) = lv;
}

// ---------------- MFMA split-fp16 GEMM ----------------
// C = elu(A@B + bias). M = CHNK rows (exact), tile 128x128, 4 waves (2x2 of 64x64).
// A: AMODE 0: packed hi/lo (chunkid = rowtile*KT + kt, 1KB lane-order chunks)
//    AMODE 1: gathered from reps hi/lo rows: row m = concat(reps[idx0[m]],reps[idx1[m]]), K=256
// Out: OMODE 0: packed hi/lo for next layer (KT_NEXT ktiles); OMODE 1: fp32 rows (N=128)
template <int KT, int NS_B, int AMODE, int OMODE, int KT_NEXT>
__global__ __launch_bounds__(256) void mfma_gemm(
    const _Float16* __restrict__ Ah, const _Float16* __restrict__ Al,
    const int* __restrict__ idx0, const int* __restrict__ idx1,
    const _Float16* __restrict__ Bh, const _Float16* __restrict__ Bl,
    const float* __restrict__ bias,
    _Float16* __restrict__ Oh, _Float16* __restrict__ Ol,
    float* __restrict__ Orows) {
  __shared__ char smem[34816] __attribute__((aligned(16)));
  _Float16* sAh = (_Float16*)smem;               // 8 KB: 8 subtiles x 1KB
  _Float16* sAl = (_Float16*)(smem + 8192);
  _Float16* sBh = (_Float16*)(smem + 16384);
  _Float16* sBl = (_Float16*)(smem + 24576);
  float* sC = (float*)smem;                      // epilogue reuse: 128 x 68

  const int tid = threadIdx.x;
  const int w = tid >> 6, lane = tid & 63;
  const int bm = blockIdx.x * 128, bn = blockIdx.y * 128;
  const int mw = (w >> 1) * 4, nw = (w & 1) * 4;
  const int bmT = bm >> 4, bnS = bn >> 4;

  f32x4 acc[4][4];
#pragma unroll
  for (int i = 0; i < 4; ++i)
#pragma unroll
    for (int j = 0; j < 4; ++j) acc[i][j] = (f32x4)0.f;

  int i0a = 0, i0b = 0, i1a = 0, i1b = 0;
  if constexpr (AMODE == 1) {
    int rr0 = bm + (w * 2) * 16 + (lane & 15);
    i0a = idx0[rr0]; i0b = idx0[rr0 + 16];
    i1a = idx1[rr0]; i1b = idx1[rr0 + 16];
  }

  for (int kt = 0; kt < KT; ++kt) {
    __syncthreads();
    if constexpr (AMODE == 0) {
#pragma unroll
      for (int s = 0; s < 2; ++s) {
        int msub = w * 2 + s;
        size_t chunk = (size_t)(bmT + msub) * KT + kt;
        dma16((const char*)Ah + chunk * 1024 + lane * 16, (char*)smem + msub * 1024);
        dma16((const char*)Al + chunk * 1024 + lane * 16, (char*)smem + 8192 + msub * 1024);
      }
    } else {
      int col = (kt & 3) * 32 + (lane >> 4) * 8;
      int r0 = (kt < 4) ? i0a : i1a;
      int r1 = (kt < 4) ? i0b : i1b;
      dma16(Ah + (size_t)r0 * HD + col, (char*)smem + (w * 2) * 1024);
      dma16(Al + (size_t)r0 * HD + col, (char*)smem + 8192 + (w * 2) * 1024);
      dma16(Ah + (size_t)r1 * HD + col, (char*)smem + (w * 2 + 1) * 1024);
      dma16(Al + (size_t)r1 * HD + col, (char*)smem + 8192 + (w * 2 + 1) * 1024);
    }
#pragma unroll
    for (int s = 0; s < 2; ++s) {
      int nsub = w * 2 + s;
      size_t chunk = (size_t)kt * NS_B + bnS + nsub;
      dma16((const char*)Bh + chunk * 1024 + lane * 16, (char*)smem + 16384 + nsub * 1024);
      dma16((const char*)Bl + chunk * 1024 + lane * 16, (char*)smem + 24576 + nsub * 1024);
    }
    __builtin_amdgcn_s_waitcnt(0);
    __syncthreads();

    f16x8 ah[4], al[4];
#pragma unroll
    for (int mi = 0; mi < 4; ++mi) {
      ah[mi] = *(const f16x8*)(sAh + (mw + mi) * 512 + lane * 8);
      al[mi] = *(const f16x8*)(sAl + (mw + mi) * 512 + lane * 8);
    }
#pragma unroll
    for (int ni = 0; ni < 4; ++ni) {
      f16x8 bh = *(const f16x8*)(sBh + (nw + ni) * 512 + lane * 8);
      f16x8 bl = *(const f16x8*)(sBl + (nw + ni) * 512 + lane * 8);
#pragma unroll
      for (int mi = 0; mi < 4; ++mi) {
        acc[mi][ni] = __builtin_amdgcn_mfma_f32_16x16x32_f16(ah[mi], bh, acc[mi][ni], 0, 0, 0);
        acc[mi][ni] = __builtin_amdgcn_mfma_f32_16x16x32_f16(al[mi], bh, acc[mi][ni], 0, 0, 0);
        acc[mi][ni] = __builtin_amdgcn_mfma_f32_16x16x32_f16(ah[mi], bl, acc[mi][ni], 0, 0, 0);
      }
    }
  }
  __syncthreads();

  if constexpr (OMODE == 1) {
    // direct fp32 row store (N == 128), C/D layout: col=lane&15, row=(lane>>4)*4+r
#pragma unroll
    for (int ni = 0; ni < 4; ++ni) {
      int colg = bn + (nw + ni) * 16 + (lane & 15);
      float bv = bias[colg];
#pragma unroll
      for (int mi = 0; mi < 4; ++mi) {
        int rowb = bm + (mw + mi) * 16 + (lane >> 4) * 4;
#pragma unroll
        for (int r = 0; r < 4; ++r)
          Orows[(size_t)(rowb + r) * 128 + colg] = elu_f(acc[mi][ni][r] + bv);
      }
    }
  } else {
    const int bnT32 = bn >> 5;
    for (int ph = 0; ph < 2; ++ph) {
      if ((w & 1) == ph) {
#pragma unroll
        for (int ni = 0; ni < 4; ++ni) {
          int colL = ni * 16 + (lane & 15);
          float bv = bias[bn + ph * 64 + colL];
#pragma unroll
          for (int mi = 0; mi < 4; ++mi) {
            int rowb = (mw + mi) * 16 + (lane >> 4) * 4;
#pragma unroll
            for (int r = 0; r < 4; ++r)
              sC[(rowb + r) * 68 + colL] = elu_f(acc[mi][ni][r] + bv);
          }
        }
      }
      __syncthreads();
#pragma unroll
      for (int c = 0; c < 4; ++c) {
        int chunkid = w * 4 + c;           // 16 chunks: 8 msubs x 2 ktiles
        int msub = chunkid >> 1, ktl = chunkid & 1;
        int m = msub * 16 + (lane & 15);
        int cb = ktl * 32 + (lane >> 4) * 8;
        f16x8 hv, lv;
#pragma unroll
        for (int j = 0; j < 8; ++j) {
          float v = sC[m * 68 + cb + j];
          _Float16 hh = (_Float16)v;
          hv[j] = hh;
          lv[j] = (_Float16)(v - (float)hh);
        }
        size_t gchunk = (size_t)(bmT + msub) * KT_NEXT + (bnT32 + ph * 2 + ktl);
        *(f16x8*)((char*)Oh + gchunk * 1024 + lane * 16) = hv;
        *(f16x8*)((char*)Ol + gchunk * 1024 + lane * 16) = lv;
      }
      __syncthreads();
    }
  }
}

// ---------------- tail: sel + segment softmax/argmax ----------------
__global__ __launch_bounds__(256) void sel_kernel(const float* __restrict__ h,
    const int* __restrict__ ei, const int* __restrict__ batchv, const int* __restrict__ yv,
    const float* __restrict__ Wp2, const float* __restrict__ bp2,
    float* __restrict__ sel, int* __restrict__ seg, int count, int chunk_off) {
  int w = blockIdx.x * 4 + (threadIdx.x >> 6);
  int lane = threadIdx.x & 63;
  if (w >= count) return;
  int eg = chunk_off + w;
  int s = ei[NOCP + eg];
  int g = batchv[s];
  int c = yv[g];
  const float* hr = h + (size_t)w * HD;
  float a = hr[lane] * Wp2[lane * 10 + c] + hr[lane + 64] * Wp2[(lane + 64) * 10 + c];
#pragma unroll
  for (int o = 32; o > 0; o >>= 1) a += __shfl_xor(a, o);
  if (lane == 0) { sel[eg] = a + bp2[c]; seg[eg] = g; }
}

__global__ __launch_bounds__(256) void segmax_sel(const float* __restrict__ sel,
    const int* __restrict__ seg, unsigned* __restrict__ mx_enc) {
  __shared__ unsigned sm[NG];
  int tid = threadIdx.x;
  if (tid < NG) sm[tid] = 0u;
  __syncthreads();
  for (int i = blockIdx.x * blockDim.x + tid; i < EAVA; i += gridDim.x * blockDim.x)
    atomicMax(&sm[seg[i]], fenc(sel[i]));
  __syncthreads();
  if (tid < NG) atomicMax(&mx_enc[tid], sm[tid]);
}

__global__ __launch_bounds__(256) void exden_kernel(const float* __restrict__ sel,
    const int* __restrict__ seg, const unsigned* __restrict__ mx_enc,
    float* __restrict__ denom, float* __restrict__ out_probs) {
  __shared__ float sd[NG];
  __shared__ float smx[NG];
  int tid = threadIdx.x;
  if (tid < NG) { smx[tid] = fdec(mx_enc[tid]); sd[tid] = 0.f; }
  __syncthreads();
  for (int i = blockIdx.x * blockDim.x + tid; i < EAVA; i += gridDim.x * blockDim.x) {
    int g = seg[i];
    float ex = expf(sel[i] - smx[g]);
    out_probs[i] = ex;
    atomicAdd(&sd[g], ex);
  }
  __syncthreads();
  if (tid < NG) atomicAdd(&denom[tid], sd[tid]);
}

__global__ __launch_bounds__(256) void probpmax_kernel(const int* __restrict__ seg,
    const float* __restrict__ denom, float* __restrict__ out_probs,
    unsigned* __restrict__ pmax_enc) {
  __shared__ float sden[NG];
  __shared__ unsigned sp[NG];
  int tid = threadIdx.x;
  if (tid < NG) { sden[tid] = denom[tid]; sp[tid] = 0u; }
  __syncthreads();
  for (int i = blockIdx.x * blockDim.x + tid; i < EAVA; i += gridDim.x * blockDim.x) {
    int g = seg[i];
    float p = out_probs[i] / sden[g];
    out_probs[i] = p;
    atomicMax(&sp[g], fenc(p));
  }
  __syncthreads();
  if (tid < NG) atomicMax(&pmax_enc[tid], sp[tid]);
}

__global__ __launch_bounds__(256) void argmin_kernel(const int* __restrict__ seg,
    const float* __restrict__ out_probs, const unsigned* __restrict__ pmax_enc,
    int* __restrict__ amin) {
  __shared__ float spm[NG];
  __shared__ int sa[NG];
  int tid = threadIdx.x;
  if (tid < NG) { spm[tid] = fdec(pmax_enc[tid]); sa[tid] = EAVA; }
  __syncthreads();
  for (int i = blockIdx.x * blockDim.x + tid; i < EAVA; i += gridDim.x * blockDim.x) {
    int g = seg[i];
    if (out_probs[i] == spm[g]) atomicMin(&sa[g], i);
  }
  __syncthreads();
  if (tid < NG) atomicMin(&amin[tid], sa[tid]);
}

__global__ void finalize_kernel(const unsigned* __restrict__ pmax_enc,
    const int* __restrict__ amin, float* __restrict__ out) {
  int g = threadIdx.x;
  if (g < NG) {
    out[EAVA + g] = fdec(pmax_enc[g]);
    out[EAVA + NG + g] = (float)amin[g];
  }
}

extern "C" void kernel_launch(void* const* d_in, const int* in_sizes, int n_in,
                              void* d_out, int out_size, void* d_ws, size_t ws_size,
                              hipStream_t stream) {
  const float* x      = (const float*)d_in[0];
  const int*   ei     = (const int*)d_in[1];
  const int*   batchv = (const int*)d_in[2];
  const int*   yv     = (const int*)d_in[3];
  const float* Wself = (const float*)d_in[5];
  const float* Wnbr  = (const float*)d_in[6];
  const float* bgnn  = (const float*)d_in[7];
  const float* Wr1   = (const float*)d_in[8];
  const float* br1   = (const float*)d_in[9];
  const float* Wr2   = (const float*)d_in[10];
  const float* br2   = (const float*)d_in[11];
  const float* Wr3   = (const float*)d_in[12];
  const float* br3   = (const float*)d_in[13];
  const float* Wp1   = (const float*)d_in[14];
  const float* bp1   = (const float*)d_in[15];
  const float* Wp2   = (const float*)d_in[16];
  const float* bp2   = (const float*)d_in[17];
  float* out = (float*)d_out;

  char* wp = (char*)d_ws;
  auto alloc = [&](size_t bytes) -> char* {
    char* p = wp;
    wp += (bytes + 255) & ~(size_t)255;
    return p;
  };
  float*     xs_all   = (float*)alloc((size_t)NN * HD * 4);
  float*     xs_ocp   = (float*)alloc((size_t)NN * HD * 4);
  float*     reps     = (float*)alloc((size_t)NN * HD * 4);
  _Float16*  reps_h   = (_Float16*)alloc((size_t)NN * HD * 2);
  _Float16*  reps_l   = (_Float16*)alloc((size_t)NN * HD * 2);
  int*       cnt      = (int*)alloc((size_t)NN * 4);
  int*       bucket   = (int*)alloc((size_t)NN * CAP * 4);
  float*     sel      = (float*)alloc((size_t)EAVA * 4);
  int*       seg      = (int*)alloc((size_t)EAVA * 4);
  unsigned*  mx_enc   = (unsigned*)alloc(NG * 4);
  float*     denom    = (float*)alloc(NG * 4);
  unsigned*  pmax_enc = (unsigned*)alloc(NG * 4);
  int*       amin     = (int*)alloc(NG * 4);
  // packed weights (hi/lo): chunk = kt*(N/16)+ns, 1KB each
  _Float16*  Wr1h = (_Float16*)alloc((size_t)8 * 32 * 1024);
  _Float16*  Wr1l = (_Float16*)alloc((size_t)8 * 32 * 1024);
  _Float16*  Wr2h = (_Float16*)alloc((size_t)16 * 16 * 1024);
  _Float16*  Wr2l = (_Float16*)alloc((size_t)16 * 16 * 1024);
  float*     W34  = (float*)alloc((size_t)256 * 128 * 4);
  float*     b34  = (float*)alloc(128 * 4);
  _Float16*  W34h = (_Float16*)alloc((size_t)8 * 8 * 1024);
  _Float16*  W34l = (_Float16*)alloc((size_t)8 * 8 * 1024);
  // per-chunk activation pack buffers
  _Float16*  b1h = (_Float16*)alloc((size_t)(CHNK / 16) * 16 * 1024);  // 2048 rowtiles x 16 ktiles
  _Float16*  b1l = (_Float16*)alloc((size_t)(CHNK / 16) * 16 * 1024);
  _Float16*  b2h = (_Float16*)alloc((size_t)(CHNK / 16) * 8 * 1024);
  _Float16*  b2l = (_Float16*)alloc((size_t)(CHNK / 16) * 8 * 1024);
  float*     hbuf = (float*)alloc((size_t)CHNK * 128 * 4);
  (void)ws_size;

  // ---- prep ----
  zero_i<<<64, 256, 0, stream>>>(cnt, NN);
  init_small<<<1, 64, 0, stream>>>(mx_enc, denom, pmax_enc, amin);
  bucket_kernel<<<NE / 256, 256, 0, stream>>>(ei, cnt, bucket);
  gather_kernel<<<(NN + 3) / 4, 256, 0, stream>>>(x, ei, cnt, bucket, xs_all, xs_ocp);
  reps_kernel<<<dim3((NN + 63) / 64, 2), 256, 0, stream>>>(x, xs_all, xs_ocp, Wself, Wnbr, bgnn, reps);
  split_reps<<<(NN * HD / 8 + 255) / 256, 256, 0, stream>>>(reps, reps_h, reps_l);
  w34_kernel<<<256, 128, 0, stream>>>(Wr3, Wp1, br3, bp1, W34, b34);
  pack_w<<<8 * 32, 64, 0, stream>>>(Wr1, 256, 512, Wr1h, Wr1l);
  pack_w<<<16 * 16, 64, 0, stream>>>(Wr2, 512, 256, Wr2h, Wr2l);
  pack_w<<<8 * 8, 64, 0, stream>>>(W34, 256, 128, W34h, W34l);

  // ---- per-edge MLP: 7 chunks of 32768 ----
  for (int c = 0; c < 7; ++c) {
    int co = c * CHNK;
    mfma_gemm<8, 32, 1, 0, 16><<<dim3(256, 4), 256, 0, stream>>>(
        reps_h, reps_l, ei + NOCP + co, ei + NE + NOCP + co, Wr1h, Wr1l, br1, b1h, b1l, nullptr);
    mfma_gemm<16, 16, 0, 0, 8><<<dim3(256, 2), 256, 0, stream>>>(
        b1h, b1l, nullptr, nullptr, Wr2h, Wr2l, br2, b2h, b2l, nullptr);
    mfma_gemm<8, 8, 0, 1, 0><<<dim3(256, 1), 256, 0, stream>>>(
        b2h, b2l, nullptr, nullptr, W34h, W34l, b34, nullptr, nullptr, hbuf);
    sel_kernel<<<CHNK / 4, 256, 0, stream>>>(hbuf, ei, batchv, yv, Wp2, bp2, sel, seg, CHNK, co);
  }

  // ---- segment softmax + argmax ----
  segmax_sel<<<112, 256, 0, stream>>>(sel, seg, mx_enc);
  exden_kernel<<<112, 256, 0, stream>>>(sel, seg, mx_enc, denom, out);
  probpmax_kernel<<<112, 256, 0, stream>>>(seg, denom, out, pmax_enc);
  argmin_kernel<<<112, 256, 0, stream>>>(seg, out, pmax_enc, amin);
  finalize_kernel<<<1, 64, 0, stream>>>(pmax_enc, amin, out);
}